// Round 12
// baseline (9618.237 us; speedup 1.0000x reference)
//
#include <hip/hip_runtime.h>
#include <hip/hip_fp16.h>

// Persistent 2D-LSTM, self-validating tagged-ring protocol (no fences/flags).
// B=64, NC=512, T=1024, K=1216 = [x 0..191 | h(t-32) 192..703 | h(t-1) 704..1215].
// 4 batch-groups x 64 col-WGs = 256 WGs x 512 thr (1 WG/CU, 112KB LDS).
// WG (g,w): batches g*16..+15, channels w*8..+7 (x4 gates = 32 gate-cols).
// h ring: fp16 [slot 64][g 4][b 16][ch 512]; u64 = 4 ch. Each fp16's LSB is
// forced to generation parity ((t>>6)&1): consumers poll data until tags match.
// Ring pre-memset to 0x01 bytes (LSB=1) != gen-0 parity (0).
// r12 = r6 + (1) x/h32 prefetch issued MID-step (after [C]), h32 validated at
// use in [B]; (2) raw s_barrier + lgkmcnt(0) instead of __syncthreads so the
// prefetch loads stay in flight across the barrier (no vmcnt(0) drain).

typedef __attribute__((ext_vector_type(8))) _Float16 half8;
typedef __attribute__((ext_vector_type(4))) float f32x4;
typedef unsigned long long u64;

#define T_ 1024

#define LDS_W    77824              // 38 chunks * 2 tiles * 64 lanes * 16B
#define LDS_PSM  33792              // f32 [2][8][16][33]
#define LDS_ALL  (LDS_W + LDS_PSM + 512)

extern __shared__ char smem[];

union U2H { u64 u[2]; half8 h; };

__global__ __launch_bounds__(512, 1) void lstm_persist(
    const float* __restrict__ x, const float* __restrict__ Wih,
    const float* __restrict__ Whh, const float* __restrict__ bih,
    const float* __restrict__ bhh, float* __restrict__ out,
    u64* ring)
{
    _Float16* Wsm = (_Float16*)smem;
    float*    Psm = (float*)(smem + LDS_W);
    float*    cst = (float*)(smem + LDS_W + LDS_PSM);

    const int tid = threadIdx.x;
    const int l   = tid & 63, wv = tid >> 6;
    const int l15 = l & 15,  l4 = l >> 4;
    const int bid = blockIdx.x;
    const int g   = bid >> 6;          // batch group 0..3
    const int w   = bid & 63;          // channel WG 0..63

    // ---- weights fp32 -> fp16 fragments in LDS (once) ----
    // tile col co = nb*16 + l15: gate = l15&3, ch_local = nb*4 + (l15>>2)
    for (int p = wv; p < 76; p += 8) {
        const int c = p >> 1, nb = p & 1;
        const int rj = (l15 & 3) * 512 + w * 8 + nb * 4 + (l15 >> 2);
        const int k  = c * 32 + l4 * 8;
        const float* src = (c < 22) ? (Wih + (size_t)rj * 704 + k)
                                    : (Whh + (size_t)rj * 512 + (k - 704));
        float4 v0 = ((const float4*)src)[0];
        float4 v1 = ((const float4*)src)[1];
        half8 hb;
        hb[0]=(_Float16)v0.x; hb[1]=(_Float16)v0.y; hb[2]=(_Float16)v0.z; hb[3]=(_Float16)v0.w;
        hb[4]=(_Float16)v1.x; hb[5]=(_Float16)v1.y; hb[6]=(_Float16)v1.z; hb[7]=(_Float16)v1.w;
        *(half8*)(Wsm + (size_t)((c * 2 + nb) * 64 + l) * 8) = hb;
    }
    if (tid < 128) cst[tid] = 0.f;

    // pointwise role (tid<128): pb = batch 0..15, pc = channel 0..7
    const int pb = tid >> 3, pc = tid & 7;
    const int gc = w * 8 + pc;
    const float bI = bih[gc]        + bhh[gc];
    const float bF = bih[512 + gc]  + bhh[512 + gc];
    const float bG = bih[1024 + gc] + bhh[1024 + gc];
    const float bO = bih[1536 + gc] + bhh[1536 + gc];
    __syncthreads();

    // per-wave chunk ownership
    const int coff = (wv + 2) & 7;
    const int gb   = g * 16 + l15;       // A-row batch
    const int rcb  = coff * 8 + l4 * 2;  // ring u64 col base ('a' frag; 'b' at +64)

    auto wfrag = [&](int c, int nb) -> half8 {
        return *(const half8*)(Wsm + (size_t)((c * 2 + nb) * 64 + l) * 8);
    };
    auto rld = [&](size_t i) -> u64 {
        return __hip_atomic_load(ring + i, __ATOMIC_RELAXED, __HIP_MEMORY_SCOPE_AGENT);
    };
    const u64 TM = 0x0001000100010001ULL;

    // blocking tagged fragment-pair load (h(t-1) consume: detect==arrival)
    auto loadfrag2 = [&](size_t ia, unsigned par_, half8& ha, half8& hb) {
        const u64 ex = par_ ? TM : 0ULL;
        u64 a0 = 0, a1 = 0, b0 = 0, b1 = 0;
        bool ok = false;
        do {
            if (!ok) {
                a0 = rld(ia);      a1 = rld(ia + 1);
                b0 = rld(ia + 64); b1 = rld(ia + 65);
                ok = ((a0 & TM) == ex) && ((a1 & TM) == ex) &&
                     ((b0 & TM) == ex) && ((b1 & TM) == ex);
            }
        } while (!__all(ok));
        U2H ca, cb;
        ca.u[0] = a0; ca.u[1] = a1; cb.u[0] = b0; cb.u[1] = b1;
        ha = ca.h; hb = cb.h;
    };

    float4 xa0, xa1;
    u64 h32a0 = 0, h32a1 = 0, h32b0 = 0, h32b1 = 0;   // h(t-32) raw prefetch

    if (wv < 6) {   // x prefetch for t=0 (y=0, xc=0)
        const int k0 = wv * 32 + l4 * 8;
        const float* xs = x + ((size_t)(gb * 3 + (k0 >> 6)) * 256 + ((k0 >> 3) & 7)) * 256;
        xa0 = ((const float4*)xs)[0];
        xa1 = ((const float4*)xs)[1];
    }

    for (int t = 0; t < T_; ++t) {
        const int par = t & 1;
        f32x4 acc0 = {0.f,0.f,0.f,0.f}, acc1 = {0.f,0.f,0.f,0.f};

        // [A] x part (prefetched regs)
        if (wv < 6) {
            half8 a;
            a[0]=(_Float16)xa0.x; a[1]=(_Float16)xa0.y; a[2]=(_Float16)xa0.z; a[3]=(_Float16)xa0.w;
            a[4]=(_Float16)xa1.x; a[5]=(_Float16)xa1.y; a[6]=(_Float16)xa1.z; a[7]=(_Float16)xa1.w;
            acc0 = __builtin_amdgcn_mfma_f32_16x16x32_f16(a, wfrag(wv,0), acc0, 0,0,0);
            acc1 = __builtin_amdgcn_mfma_f32_16x16x32_f16(a, wfrag(wv,1), acc1, 0,0,0);
        }
        // [B] h(t-32): validate mid-prev-step-issued regs (rare retry), then MFMA
        if (t >= 32) {
            const u64 ex = (((t - 32) >> 6) & 1) ? TM : 0ULL;
            bool ok = ((h32a0 & TM) == ex) && ((h32a1 & TM) == ex) &&
                      ((h32b0 & TM) == ex) && ((h32b1 & TM) == ex);
            if (!__all(ok)) {
                const size_t ia = ((size_t)(((t - 32) & 63) * 4 + g) * 16 + l15) * 128 + rcb;
                do {
                    if (!ok) {
                        h32a0 = rld(ia);      h32a1 = rld(ia + 1);
                        h32b0 = rld(ia + 64); h32b1 = rld(ia + 65);
                        ok = ((h32a0 & TM) == ex) && ((h32a1 & TM) == ex) &&
                             ((h32b0 & TM) == ex) && ((h32b1 & TM) == ex);
                    }
                } while (!__all(ok));
            }
            U2H ca, cb;
            ca.u[0] = h32a0; ca.u[1] = h32a1;
            cb.u[0] = h32b0; cb.u[1] = h32b1;
            acc0 = __builtin_amdgcn_mfma_f32_16x16x32_f16(ca.h, wfrag(6+coff,0),  acc0, 0,0,0);
            acc1 = __builtin_amdgcn_mfma_f32_16x16x32_f16(ca.h, wfrag(6+coff,1),  acc1, 0,0,0);
            acc0 = __builtin_amdgcn_mfma_f32_16x16x32_f16(cb.h, wfrag(14+coff,0), acc0, 0,0,0);
            acc1 = __builtin_amdgcn_mfma_f32_16x16x32_f16(cb.h, wfrag(14+coff,1), acc1, 0,0,0);
        }
        // [C] h(t-1): blocking tagged poll (r6 semantics: detect == data-in-hand)
        if (t > 0) {
            const size_t iaP = ((size_t)(((t - 1) & 63) * 4 + g) * 16 + l15) * 128 + rcb;
            half8 ha, hb;
            loadfrag2(iaP, ((t - 1) >> 6) & 1, ha, hb);
            acc0 = __builtin_amdgcn_mfma_f32_16x16x32_f16(ha, wfrag(22+coff,0), acc0, 0,0,0);
            acc1 = __builtin_amdgcn_mfma_f32_16x16x32_f16(ha, wfrag(22+coff,1), acc1, 0,0,0);
            acc0 = __builtin_amdgcn_mfma_f32_16x16x32_f16(hb, wfrag(30+coff,0), acc0, 0,0,0);
            acc1 = __builtin_amdgcn_mfma_f32_16x16x32_f16(hb, wfrag(30+coff,1), acc1, 0,0,0);
        }

        // [P] prefetch for t+1, issued MID-STEP (fire-and-forget; stays in
        // flight across the raw barrier; ~1300cy before use at next [A]/[B])
        const int tn = t + 1;
        if (tn < T_) {
            if (wv < 6) {
                const int yn = tn >> 5, xcn = tn & 31;
                const int k0 = wv * 32 + l4 * 8;
                const float* xs = x + ((size_t)(gb * 3 + (k0 >> 6)) * 256
                                       + yn * 8 + ((k0 >> 3) & 7)) * 256 + xcn * 8;
                xa0 = ((const float4*)xs)[0];
                xa1 = ((const float4*)xs)[1];
            }
            if (tn >= 32) {
                const size_t ia = ((size_t)(((tn - 32) & 63) * 4 + g) * 16 + l15) * 128 + rcb;
                h32a0 = rld(ia);      h32a1 = rld(ia + 1);
                h32b0 = rld(ia + 64); h32b1 = rld(ia + 65);
            }
        }

        // [D] partials -> LDS (parity double-buffer)
        {
            float* Pw = Psm + (size_t)((par * 8 + wv) * 16) * 33;
#pragma unroll
            for (int r = 0; r < 4; ++r) {
                Pw[(l4 * 4 + r) * 33 + l15]      = acc0[r];
                Pw[(l4 * 4 + r) * 33 + 16 + l15] = acc1[r];
            }
        }
        // [E] raw barrier: order LDS writes, do NOT drain vmcnt (prefetch lives)
        __asm__ volatile("s_waitcnt lgkmcnt(0)" ::: "memory");
        __builtin_amdgcn_s_barrier();
        __asm__ volatile("" ::: "memory");

        // [F] pointwise + tagged publish (waves 0-1); waves 2-7 run ahead
        if (tid < 128) {
            float gi = bI, gf = bF, gg = bG, go = bO;
#pragma unroll
            for (int q = 0; q < 8; ++q) {
                const float* Pq = Psm + ((size_t)((par * 8 + q) * 16 + pb)) * 33 + pc * 4;
                gi += Pq[0]; gf += Pq[1]; gg += Pq[2]; go += Pq[3];
            }
            const float cprev = cst[tid];
            const float si = 1.f / (1.f + __expf(-gi));
            const float sf = 1.f / (1.f + __expf(-gf));
            const float so = 1.f / (1.f + __expf(-go));
            const float tg = 2.f / (1.f + __expf(-2.f * gg)) - 1.f;
            const float cn = sf * cprev + si * tg;
            const float th = 2.f / (1.f + __expf(-2.f * cn)) - 1.f;
            const float hn = so * th;
            cst[tid] = cn;

            union { _Float16 f; unsigned short s; } cv; cv.f = (_Float16)hn;
            unsigned hb16 = ((unsigned)cv.s & ~1u) | (unsigned)((t >> 6) & 1);  // force tag
            unsigned other = (unsigned)__shfl_xor((int)hb16, 1);
            unsigned pairv = (pc & 1) ? ((other & 0xffffu) | (hb16 << 16))
                                      : ((hb16 & 0xffffu) | (other << 16));
            unsigned hi = (unsigned)__shfl_xor((int)pairv, 2);
            if ((pc & 3) == 0) {
                u64 val = (u64)pairv | ((u64)hi << 32);
                const size_t idx = ((size_t)((t & 63) * 4 + g) * 16 + pb) * 128
                                 + w * 2 + (pc >> 2);
                __hip_atomic_store(ring + idx, val, __ATOMIC_RELAXED,
                                   __HIP_MEMORY_SCOPE_AGENT);
            }
            out[(size_t)(g * 16 + pb) * (T_ * 512) + (size_t)t * 512 + gc] = hn;
        }
    }
}

extern "C" void kernel_launch(void* const* d_in, const int* in_sizes, int n_in,
                              void* d_out, int out_size, void* d_ws, size_t ws_size,
                              hipStream_t stream) {
    const float* x   = (const float*)d_in[0];
    const float* Wih = (const float*)d_in[1];
    const float* Whh = (const float*)d_in[2];
    const float* bih = (const float*)d_in[3];
    const float* bhh = (const float*)d_in[4];
    float* out = (float*)d_out;

    u64* ring = (u64*)d_ws;   // 64*4*16*128 u64 = 4 MB

    // LSB pattern 1 everywhere != gen-0 parity 0
    hipMemsetAsync(ring, 0x01, 64ull * 4 * 16 * 128 * 8, stream);

    (void)hipFuncSetAttribute((const void*)lstm_persist,
                              hipFuncAttributeMaxDynamicSharedMemorySize, LDS_ALL);

    hipLaunchKernelGGL(lstm_persist, dim3(256), dim3(512), LDS_ALL, stream,
                       x, Wih, Whh, bih, bhh, out, ring);
}

// Round 13
// 3175.615 us; speedup vs baseline: 3.0288x; 3.0288x over previous
//
#include <hip/hip_runtime.h>
#include <hip/hip_fp16.h>

// Persistent 2D-LSTM, self-validating tagged-ring protocol (no fences/flags).
// B=64, NC=512, T=1024, K=1216 = [x 0..191 | h(t-32) 192..703 | h(t-1) 704..1215].
// 4 batch-groups x 64 col-WGs = 256 WGs x 512 thr (1 WG/CU, 112KB LDS).
// WG (g,w): batches g*16..+15, channels w*8..+7 (x4 gates = 32 gate-cols).
// h ring: fp16 [slot 64][g 4][b 16][ch 512]; u64 = 4 ch. Each fp16's LSB is
// forced to generation parity ((t>>6)&1): consumers poll data until tags match.
// Ring pre-memset to 0x01 bytes (LSB=1) != gen-0 parity (0).
// r13 = r6 + ONE line: s_sleep(1) backoff at the top of each poll RETRY round
// (round 0 untouched). Cuts MALL poll congestion without adding serial hops
// (r11 lesson) or premature issue (r8/r10/r12 lesson).

typedef __attribute__((ext_vector_type(8))) _Float16 half8;
typedef __attribute__((ext_vector_type(4))) float f32x4;
typedef unsigned long long u64;

#define T_ 1024

#define LDS_W    77824              // 38 chunks * 2 tiles * 64 lanes * 16B
#define LDS_PSM  33792              // f32 [2][8][16][33]
#define LDS_ALL  (LDS_W + LDS_PSM + 512)

extern __shared__ char smem[];

__global__ __launch_bounds__(512, 1) void lstm_persist(
    const float* __restrict__ x, const float* __restrict__ Wih,
    const float* __restrict__ Whh, const float* __restrict__ bih,
    const float* __restrict__ bhh, float* __restrict__ out,
    u64* ring)
{
    _Float16* Wsm = (_Float16*)smem;
    float*    Psm = (float*)(smem + LDS_W);
    float*    cst = (float*)(smem + LDS_W + LDS_PSM);

    const int tid = threadIdx.x;
    const int l   = tid & 63, wv = tid >> 6;
    const int l15 = l & 15,  l4 = l >> 4;
    const int bid = blockIdx.x;
    const int g   = bid >> 6;          // batch group 0..3
    const int w   = bid & 63;          // channel WG 0..63

    // ---- weights fp32 -> fp16 fragments in LDS (once) ----
    // tile col co = nb*16 + l15: gate = l15&3, ch_local = nb*4 + (l15>>2)
    for (int p = wv; p < 76; p += 8) {
        const int c = p >> 1, nb = p & 1;
        const int rj = (l15 & 3) * 512 + w * 8 + nb * 4 + (l15 >> 2);
        const int k  = c * 32 + l4 * 8;
        const float* src = (c < 22) ? (Wih + (size_t)rj * 704 + k)
                                    : (Whh + (size_t)rj * 512 + (k - 704));
        float4 v0 = ((const float4*)src)[0];
        float4 v1 = ((const float4*)src)[1];
        half8 hb;
        hb[0]=(_Float16)v0.x; hb[1]=(_Float16)v0.y; hb[2]=(_Float16)v0.z; hb[3]=(_Float16)v0.w;
        hb[4]=(_Float16)v1.x; hb[5]=(_Float16)v1.y; hb[6]=(_Float16)v1.z; hb[7]=(_Float16)v1.w;
        *(half8*)(Wsm + (size_t)((c * 2 + nb) * 64 + l) * 8) = hb;
    }
    if (tid < 128) cst[tid] = 0.f;

    // pointwise role (tid<128): pb = batch 0..15, pc = channel 0..7
    const int pb = tid >> 3, pc = tid & 7;
    const int gc = w * 8 + pc;
    const float bI = bih[gc]        + bhh[gc];
    const float bF = bih[512 + gc]  + bhh[512 + gc];
    const float bG = bih[1024 + gc] + bhh[1024 + gc];
    const float bO = bih[1536 + gc] + bhh[1536 + gc];
    __syncthreads();

    // per-wave chunk ownership: all c in 0..37 with c%8 == wv
    const int coff = (wv + 2) & 7;
    const int c32a = 6 + coff,  c32b = 14 + coff;   // h(t-32) chunks
    const int c1a  = 22 + coff, c1b  = 30 + coff;   // h(t-1) chunks
    const int gb   = g * 16 + l15;                  // A-row batch

    auto wfrag = [&](int c, int nb) -> half8 {
        return *(const half8*)(Wsm + (size_t)((c * 2 + nb) * 64 + l) * 8);
    };
    // tagged ring fragment load: round 0 immediate; retries backoff-spaced.
    auto loadfrag = [&](int slot, int col, unsigned par_) -> half8 {
        const size_t idx = ((size_t)(slot * 4 + g) * 16 + l15) * 128 + col + l4 * 2;
        const u64 M  = 0x0001000100010001ULL;
        const u64 ex = par_ ? M : 0ULL;
        u64 v0 = __hip_atomic_load(ring + idx,     __ATOMIC_RELAXED, __HIP_MEMORY_SCOPE_AGENT);
        u64 v1 = __hip_atomic_load(ring + idx + 1, __ATOMIC_RELAXED, __HIP_MEMORY_SCOPE_AGENT);
        bool ok = ((v0 & M) == ex) && ((v1 & M) == ex);
        while (!__all(ok)) {
            __builtin_amdgcn_s_sleep(1);   // r13: space out retry rounds
            if (!ok) {
                v0 = __hip_atomic_load(ring + idx,     __ATOMIC_RELAXED, __HIP_MEMORY_SCOPE_AGENT);
                v1 = __hip_atomic_load(ring + idx + 1, __ATOMIC_RELAXED, __HIP_MEMORY_SCOPE_AGENT);
                ok = ((v0 & M) == ex) && ((v1 & M) == ex);
            }
        }
        union { u64 u[2]; half8 h; } cc;
        cc.u[0] = v0; cc.u[1] = v1;
        return cc.h;
    };

    float4 xa0, xa1;
    half8  h32a, h32b;
    if (wv < 6) {   // x prefetch for t=0 (y=0, xc=0)
        const int k0 = wv * 32 + l4 * 8;
        const float* xs = x + ((size_t)(gb * 3 + (k0 >> 6)) * 256 + ((k0 >> 3) & 7)) * 256;
        xa0 = ((const float4*)xs)[0];
        xa1 = ((const float4*)xs)[1];
    }

    for (int t = 0; t < T_; ++t) {
        const int par = t & 1;
        f32x4 acc0 = {0.f,0.f,0.f,0.f}, acc1 = {0.f,0.f,0.f,0.f};

        // [A] x part (prefetched regs)
        if (wv < 6) {
            half8 a;
            a[0]=(_Float16)xa0.x; a[1]=(_Float16)xa0.y; a[2]=(_Float16)xa0.z; a[3]=(_Float16)xa0.w;
            a[4]=(_Float16)xa1.x; a[5]=(_Float16)xa1.y; a[6]=(_Float16)xa1.z; a[7]=(_Float16)xa1.w;
            acc0 = __builtin_amdgcn_mfma_f32_16x16x32_f16(a, wfrag(wv,0), acc0, 0,0,0);
            acc1 = __builtin_amdgcn_mfma_f32_16x16x32_f16(a, wfrag(wv,1), acc1, 0,0,0);
        }
        // [B] h(t-32) part (prefetched regs)
        if (t >= 32) {
            acc0 = __builtin_amdgcn_mfma_f32_16x16x32_f16(h32a, wfrag(c32a,0), acc0, 0,0,0);
            acc1 = __builtin_amdgcn_mfma_f32_16x16x32_f16(h32a, wfrag(c32a,1), acc1, 0,0,0);
            acc0 = __builtin_amdgcn_mfma_f32_16x16x32_f16(h32b, wfrag(c32b,0), acc0, 0,0,0);
            acc1 = __builtin_amdgcn_mfma_f32_16x16x32_f16(h32b, wfrag(c32b,1), acc1, 0,0,0);
        }
        // [C] h(t-1): tagged wait + MFMA (the only real stall)
        if (t > 0) {
            const int sP = (t - 1) & 63;
            const unsigned p1 = ((t - 1) >> 6) & 1;
            half8 ha = loadfrag(sP, (c1a - 22) * 8, p1);
            acc0 = __builtin_amdgcn_mfma_f32_16x16x32_f16(ha, wfrag(c1a,0), acc0, 0,0,0);
            acc1 = __builtin_amdgcn_mfma_f32_16x16x32_f16(ha, wfrag(c1a,1), acc1, 0,0,0);
            half8 hb = loadfrag(sP, (c1b - 22) * 8, p1);
            acc0 = __builtin_amdgcn_mfma_f32_16x16x32_f16(hb, wfrag(c1b,0), acc0, 0,0,0);
            acc1 = __builtin_amdgcn_mfma_f32_16x16x32_f16(hb, wfrag(c1b,1), acc1, 0,0,0);
        }

        // [D] partials -> LDS (parity double-buffer)
        {
            float* Pw = Psm + (size_t)((par * 8 + wv) * 16) * 33;
#pragma unroll
            for (int r = 0; r < 4; ++r) {
                Pw[(l4 * 4 + r) * 33 + l15]      = acc0[r];
                Pw[(l4 * 4 + r) * 33 + 16 + l15] = acc1[r];
            }
        }
        __syncthreads();   // [E] the only barrier per step

        // [F] pointwise + tagged publish (waves 0-1); waves 2-7 run ahead
        if (tid < 128) {
            float gi = bI, gf = bF, gg = bG, go = bO;
#pragma unroll
            for (int q = 0; q < 8; ++q) {
                const float* Pq = Psm + ((size_t)((par * 8 + q) * 16 + pb)) * 33 + pc * 4;
                gi += Pq[0]; gf += Pq[1]; gg += Pq[2]; go += Pq[3];
            }
            const float cprev = cst[tid];
            const float si = 1.f / (1.f + __expf(-gi));
            const float sf = 1.f / (1.f + __expf(-gf));
            const float so = 1.f / (1.f + __expf(-go));
            const float tg = 2.f / (1.f + __expf(-2.f * gg)) - 1.f;
            const float cn = sf * cprev + si * tg;
            const float th = 2.f / (1.f + __expf(-2.f * cn)) - 1.f;
            const float hn = so * th;
            cst[tid] = cn;

            union { _Float16 f; unsigned short s; } cv; cv.f = (_Float16)hn;
            unsigned hb16 = ((unsigned)cv.s & ~1u) | (unsigned)((t >> 6) & 1);  // force tag
            unsigned other = (unsigned)__shfl_xor((int)hb16, 1);
            unsigned pairv = (pc & 1) ? ((other & 0xffffu) | (hb16 << 16))
                                      : ((hb16 & 0xffffu) | (other << 16));
            unsigned hi = (unsigned)__shfl_xor((int)pairv, 2);
            if ((pc & 3) == 0) {
                u64 val = (u64)pairv | ((u64)hi << 32);
                const size_t idx = ((size_t)((t & 63) * 4 + g) * 16 + pb) * 128
                                 + w * 2 + (pc >> 2);
                __hip_atomic_store(ring + idx, val, __ATOMIC_RELAXED,
                                   __HIP_MEMORY_SCOPE_AGENT);
            }
            out[(size_t)(g * 16 + pb) * (T_ * 512) + (size_t)t * 512 + gc] = hn;
        }

        // [G/H] prefetch next step: x and h(t+1-32) (31-step-old => no stall)
        const int tn = t + 1;
        if (tn < T_) {
            if (wv < 6) {
                const int yn = tn >> 5, xcn = tn & 31;
                const int k0 = wv * 32 + l4 * 8;
                const float* xs = x + ((size_t)(gb * 3 + (k0 >> 6)) * 256
                                       + yn * 8 + ((k0 >> 3) & 7)) * 256 + xcn * 8;
                xa0 = ((const float4*)xs)[0];
                xa1 = ((const float4*)xs)[1];
            }
            if (tn >= 32) {
                const int sO = (tn - 32) & 63;
                const unsigned p32 = ((tn - 32) >> 6) & 1;
                h32a = loadfrag(sO, (c32a - 6) * 8, p32);
                h32b = loadfrag(sO, (c32b - 6) * 8, p32);
            }
        }
    }
}

extern "C" void kernel_launch(void* const* d_in, const int* in_sizes, int n_in,
                              void* d_out, int out_size, void* d_ws, size_t ws_size,
                              hipStream_t stream) {
    const float* x   = (const float*)d_in[0];
    const float* Wih = (const float*)d_in[1];
    const float* Whh = (const float*)d_in[2];
    const float* bih = (const float*)d_in[3];
    const float* bhh = (const float*)d_in[4];
    float* out = (float*)d_out;

    u64* ring = (u64*)d_ws;   // 64*4*16*128 u64 = 4 MB

    // LSB pattern 1 everywhere != gen-0 parity 0
    hipMemsetAsync(ring, 0x01, 64ull * 4 * 16 * 128 * 8, stream);

    (void)hipFuncSetAttribute((const void*)lstm_persist,
                              hipFuncAttributeMaxDynamicSharedMemorySize, LDS_ALL);

    hipLaunchKernelGGL(lstm_persist, dim3(256), dim3(512), LDS_ALL, stream,
                       x, Wih, Whh, bih, bhh, out, ring);
}

// Round 14
// 2441.464 us; speedup vs baseline: 3.9395x; 1.3007x over previous
//
#include <hip/hip_runtime.h>
#include <hip/hip_fp16.h>

// Persistent 2D-LSTM, self-validating tagged-ring protocol (no fences/flags).
// B=64, NC=512, T=1024, K=1216 = [x 0..191 | h(t-32) 192..703 | h(t-1) 704..1215].
// 4 batch-groups x 64 col-WGs = 256 WGs x 512 thr (1 WG/CU, 112KB LDS).
// WG (g,w): batches g*16..+15, channels w*8..+7 (x4 gates = 32 gate-cols).
// r14: ring stored FRAGMENT-MAJOR for coalesced MALL access:
//   per (slot,g) block (2048 u64): u64 idx = chunk*128 + 2*lane (+0/+1),
//   i.e. [chunk 16][l4 4][batch 16][8 halfs]. Consumer wave reads 1KB
//   contiguous per chunk (16 line-trans vs 128 scattered); producer WG writes
//   256B contiguous (4 trans vs 32). Protocol unchanged: fp16 LSB = generation
//   parity ((t>>6)&1), blocking tagged polls, ring pre-memset 0x01.

typedef __attribute__((ext_vector_type(8))) _Float16 half8;
typedef __attribute__((ext_vector_type(4))) float f32x4;
typedef unsigned long long u64;

#define T_ 1024

#define LDS_W    77824              // 38 chunks * 2 tiles * 64 lanes * 16B
#define LDS_PSM  33792              // f32 [2][8][16][33]
#define LDS_ALL  (LDS_W + LDS_PSM + 512)

extern __shared__ char smem[];

__global__ __launch_bounds__(512, 1) void lstm_persist(
    const float* __restrict__ x, const float* __restrict__ Wih,
    const float* __restrict__ Whh, const float* __restrict__ bih,
    const float* __restrict__ bhh, float* __restrict__ out,
    u64* ring)
{
    _Float16* Wsm = (_Float16*)smem;
    float*    Psm = (float*)(smem + LDS_W);
    float*    cst = (float*)(smem + LDS_W + LDS_PSM);

    const int tid = threadIdx.x;
    const int l   = tid & 63, wv = tid >> 6;
    const int l15 = l & 15,  l4 = l >> 4;
    const int bid = blockIdx.x;
    const int g   = bid >> 6;          // batch group 0..3
    const int w   = bid & 63;          // channel WG 0..63

    // ---- weights fp32 -> fp16 fragments in LDS (once) ----
    // tile col co = nb*16 + l15: gate = l15&3, ch_local = nb*4 + (l15>>2)
    for (int p = wv; p < 76; p += 8) {
        const int c = p >> 1, nb = p & 1;
        const int rj = (l15 & 3) * 512 + w * 8 + nb * 4 + (l15 >> 2);
        const int k  = c * 32 + l4 * 8;
        const float* src = (c < 22) ? (Wih + (size_t)rj * 704 + k)
                                    : (Whh + (size_t)rj * 512 + (k - 704));
        float4 v0 = ((const float4*)src)[0];
        float4 v1 = ((const float4*)src)[1];
        half8 hb;
        hb[0]=(_Float16)v0.x; hb[1]=(_Float16)v0.y; hb[2]=(_Float16)v0.z; hb[3]=(_Float16)v0.w;
        hb[4]=(_Float16)v1.x; hb[5]=(_Float16)v1.y; hb[6]=(_Float16)v1.z; hb[7]=(_Float16)v1.w;
        *(half8*)(Wsm + (size_t)((c * 2 + nb) * 64 + l) * 8) = hb;
    }
    if (tid < 128) cst[tid] = 0.f;

    // pointwise role (tid<128): pb = batch 0..15, pc = channel 0..7
    const int pb = tid >> 3, pc = tid & 7;
    const int gc = w * 8 + pc;
    const float bI = bih[gc]        + bhh[gc];
    const float bF = bih[512 + gc]  + bhh[512 + gc];
    const float bG = bih[1024 + gc] + bhh[1024 + gc];
    const float bO = bih[1536 + gc] + bhh[1536 + gc];
    __syncthreads();

    // per-wave chunk ownership: all c in 0..37 with c%8 == wv
    const int coff = (wv + 2) & 7;
    const int c32a = 6 + coff,  c32b = 14 + coff;   // h(t-32) chunks
    const int c1a  = 22 + coff, c1b  = 30 + coff;   // h(t-1) chunks
    const int gb   = g * 16 + l15;                  // A-row batch

    auto wfrag = [&](int c, int nb) -> half8 {
        return *(const half8*)(Wsm + (size_t)((c * 2 + nb) * 64 + l) * 8);
    };
    // tagged ring fragment load, fragment-major layout:
    // u64 idx = (slot*4+g)*2048 + cc*128 + 2*lane (+0/+1) -- wave reads 1KB contig.
    auto loadfrag = [&](int slot, int cc, unsigned par_) -> half8 {
        const size_t idx = ((size_t)(slot * 4 + g)) * 2048 + (size_t)cc * 128 + 2 * l;
        const u64 M  = 0x0001000100010001ULL;
        const u64 ex = par_ ? M : 0ULL;
        u64 v0 = __hip_atomic_load(ring + idx,     __ATOMIC_RELAXED, __HIP_MEMORY_SCOPE_AGENT);
        u64 v1 = __hip_atomic_load(ring + idx + 1, __ATOMIC_RELAXED, __HIP_MEMORY_SCOPE_AGENT);
        bool ok = ((v0 & M) == ex) && ((v1 & M) == ex);
        while (!__all(ok)) {
            __builtin_amdgcn_s_sleep(1);   // space out retry rounds
            if (!ok) {
                v0 = __hip_atomic_load(ring + idx,     __ATOMIC_RELAXED, __HIP_MEMORY_SCOPE_AGENT);
                v1 = __hip_atomic_load(ring + idx + 1, __ATOMIC_RELAXED, __HIP_MEMORY_SCOPE_AGENT);
                ok = ((v0 & M) == ex) && ((v1 & M) == ex);
            }
        }
        union { u64 u[2]; half8 h; } cc_;
        cc_.u[0] = v0; cc_.u[1] = v1;
        return cc_.h;
    };

    float4 xa0, xa1;
    half8  h32a, h32b;
    if (wv < 6) {   // x prefetch for t=0 (y=0, xc=0)
        const int k0 = wv * 32 + l4 * 8;
        const float* xs = x + ((size_t)(gb * 3 + (k0 >> 6)) * 256 + ((k0 >> 3) & 7)) * 256;
        xa0 = ((const float4*)xs)[0];
        xa1 = ((const float4*)xs)[1];
    }

    for (int t = 0; t < T_; ++t) {
        const int par = t & 1;
        f32x4 acc0 = {0.f,0.f,0.f,0.f}, acc1 = {0.f,0.f,0.f,0.f};

        // [A] x part (prefetched regs)
        if (wv < 6) {
            half8 a;
            a[0]=(_Float16)xa0.x; a[1]=(_Float16)xa0.y; a[2]=(_Float16)xa0.z; a[3]=(_Float16)xa0.w;
            a[4]=(_Float16)xa1.x; a[5]=(_Float16)xa1.y; a[6]=(_Float16)xa1.z; a[7]=(_Float16)xa1.w;
            acc0 = __builtin_amdgcn_mfma_f32_16x16x32_f16(a, wfrag(wv,0), acc0, 0,0,0);
            acc1 = __builtin_amdgcn_mfma_f32_16x16x32_f16(a, wfrag(wv,1), acc1, 0,0,0);
        }
        // [B] h(t-32) part (prefetched regs)
        if (t >= 32) {
            acc0 = __builtin_amdgcn_mfma_f32_16x16x32_f16(h32a, wfrag(c32a,0), acc0, 0,0,0);
            acc1 = __builtin_amdgcn_mfma_f32_16x16x32_f16(h32a, wfrag(c32a,1), acc1, 0,0,0);
            acc0 = __builtin_amdgcn_mfma_f32_16x16x32_f16(h32b, wfrag(c32b,0), acc0, 0,0,0);
            acc1 = __builtin_amdgcn_mfma_f32_16x16x32_f16(h32b, wfrag(c32b,1), acc1, 0,0,0);
        }
        // [C] h(t-1): tagged wait + MFMA (the only real stall)
        if (t > 0) {
            const int sP = (t - 1) & 63;
            const unsigned p1 = ((t - 1) >> 6) & 1;
            half8 ha = loadfrag(sP, c1a - 22, p1);
            acc0 = __builtin_amdgcn_mfma_f32_16x16x32_f16(ha, wfrag(c1a,0), acc0, 0,0,0);
            acc1 = __builtin_amdgcn_mfma_f32_16x16x32_f16(ha, wfrag(c1a,1), acc1, 0,0,0);
            half8 hb = loadfrag(sP, c1b - 22, p1);
            acc0 = __builtin_amdgcn_mfma_f32_16x16x32_f16(hb, wfrag(c1b,0), acc0, 0,0,0);
            acc1 = __builtin_amdgcn_mfma_f32_16x16x32_f16(hb, wfrag(c1b,1), acc1, 0,0,0);
        }

        // [D] partials -> LDS (parity double-buffer)
        {
            float* Pw = Psm + (size_t)((par * 8 + wv) * 16) * 33;
#pragma unroll
            for (int r = 0; r < 4; ++r) {
                Pw[(l4 * 4 + r) * 33 + l15]      = acc0[r];
                Pw[(l4 * 4 + r) * 33 + 16 + l15] = acc1[r];
            }
        }
        __syncthreads();   // [E] the only barrier per step

        // [F] pointwise + tagged publish (waves 0-1); waves 2-7 run ahead
        if (tid < 128) {
            float gi = bI, gf = bF, gg = bG, go = bO;
#pragma unroll
            for (int q = 0; q < 8; ++q) {
                const float* Pq = Psm + ((size_t)((par * 8 + q) * 16 + pb)) * 33 + pc * 4;
                gi += Pq[0]; gf += Pq[1]; gg += Pq[2]; go += Pq[3];
            }
            const float cprev = cst[tid];
            const float si = 1.f / (1.f + __expf(-gi));
            const float sf = 1.f / (1.f + __expf(-gf));
            const float so = 1.f / (1.f + __expf(-go));
            const float tg = 2.f / (1.f + __expf(-2.f * gg)) - 1.f;
            const float cn = sf * cprev + si * tg;
            const float th = 2.f / (1.f + __expf(-2.f * cn)) - 1.f;
            const float hn = so * th;
            cst[tid] = cn;

            union { _Float16 f; unsigned short s; } cv; cv.f = (_Float16)hn;
            unsigned hb16 = ((unsigned)cv.s & ~1u) | (unsigned)((t >> 6) & 1);  // force tag
            unsigned other = (unsigned)__shfl_xor((int)hb16, 1);
            unsigned pairv = (pc & 1) ? ((other & 0xffffu) | (hb16 << 16))
                                      : ((hb16 & 0xffffu) | (other << 16));
            unsigned hi = (unsigned)__shfl_xor((int)pairv, 2);
            if ((pc & 3) == 0) {
                u64 val = (u64)pairv | ((u64)hi << 32);
                // fragment-major publish: u64 idx = block + w*32 + pb*2 + (pc>>2)
                const size_t idx = ((size_t)((t & 63) * 4 + g)) * 2048
                                 + (size_t)w * 32 + (size_t)pb * 2 + (pc >> 2);
                __hip_atomic_store(ring + idx, val, __ATOMIC_RELAXED,
                                   __HIP_MEMORY_SCOPE_AGENT);
            }
            out[(size_t)(g * 16 + pb) * (T_ * 512) + (size_t)t * 512 + gc] = hn;
        }

        // [G/H] prefetch next step: x and h(t+1-32) (31-step-old => no stall)
        const int tn = t + 1;
        if (tn < T_) {
            if (wv < 6) {
                const int yn = tn >> 5, xcn = tn & 31;
                const int k0 = wv * 32 + l4 * 8;
                const float* xs = x + ((size_t)(gb * 3 + (k0 >> 6)) * 256
                                       + yn * 8 + ((k0 >> 3) & 7)) * 256 + xcn * 8;
                xa0 = ((const float4*)xs)[0];
                xa1 = ((const float4*)xs)[1];
            }
            if (tn >= 32) {
                const int sO = (tn - 32) & 63;
                const unsigned p32 = ((tn - 32) >> 6) & 1;
                h32a = loadfrag(sO, c32a - 6, p32);
                h32b = loadfrag(sO, c32b - 6, p32);
            }
        }
    }
}

extern "C" void kernel_launch(void* const* d_in, const int* in_sizes, int n_in,
                              void* d_out, int out_size, void* d_ws, size_t ws_size,
                              hipStream_t stream) {
    const float* x   = (const float*)d_in[0];
    const float* Wih = (const float*)d_in[1];
    const float* Whh = (const float*)d_in[2];
    const float* bih = (const float*)d_in[3];
    const float* bhh = (const float*)d_in[4];
    float* out = (float*)d_out;

    u64* ring = (u64*)d_ws;   // 64*4*2048 u64 = 4 MB

    // LSB pattern 1 everywhere != gen-0 parity 0
    hipMemsetAsync(ring, 0x01, 64ull * 4 * 2048 * 8, stream);

    (void)hipFuncSetAttribute((const void*)lstm_persist,
                              hipFuncAttributeMaxDynamicSharedMemorySize, LDS_ALL);

    hipLaunchKernelGGL(lstm_persist, dim3(256), dim3(512), LDS_ALL, stream,
                       x, Wih, Whh, bih, bhh, out, ring);
}